// Round 1
// baseline (872.085 us; speedup 1.0000x reference)
//
#include <hip/hip_runtime.h>
#include <math.h>

// QCQP via FISTA, one workgroup per batch, H = P^T P held entirely in VGPRs.
// B=512, N=256, NC=128, 20 power iters, 100 FISTA iters.
//
// Thread t (0..255): c = t>>5 (column block, 32 cols), r = t&31 (row block, 8 rows).
// h[e*32+j] = H[r*8+e][c*32+j]. Matvec partials reduced via shfl_xor(32) then LDS.

namespace {

constexpr int NDIM = 256;
constexpr int NCON = 128;
constexpr int PITERS = 20;
constexpr int FITERS = 100;

struct Smem {
    float Ps[32 * 256];   // 32 KB P-row staging
    float vec[256];       // v (power) / y (FISTA)
    float red[4 * 256];   // cross-wave matvec reduction
    float zz[256];        // pre-projection iterate
    float scal[8];        // scalar reductions
};

// (H x)_i for i = threadIdx.x, given x in LDS (barrier-consistent on entry).
// Contains one internal __syncthreads(); caller must barrier again before the
// next call so red[] isn't overwritten while being read (the loop bodies below
// always do).
__device__ __forceinline__ float matvec_row(const float (&h)[256],
                                            const float* __restrict__ xv,
                                            float* __restrict__ red,
                                            int t, int c, int wave, int lane)
{
    float xr[32];
    const float4* xp = (const float4*)(xv + c * 32);
#pragma unroll
    for (int jj = 0; jj < 8; ++jj) {
        float4 v4 = xp[jj];
        xr[jj * 4 + 0] = v4.x; xr[jj * 4 + 1] = v4.y;
        xr[jj * 4 + 2] = v4.z; xr[jj * 4 + 3] = v4.w;
    }
    float pw[8];
#pragma unroll
    for (int e = 0; e < 8; ++e) pw[e] = 0.0f;
#pragma unroll
    for (int e = 0; e < 8; ++e)
#pragma unroll
        for (int j = 0; j < 32; ++j)
            pw[e] = fmaf(h[e * 32 + j], xr[j], pw[e]);
    // pair-reduce across lanes l and l^32 (same r, adjacent c)
#pragma unroll
    for (int e = 0; e < 8; ++e) pw[e] += __shfl_xor(pw[e], 32);
    if (lane < 32) {
#pragma unroll
        for (int e = 0; e < 8; ++e) red[wave * 256 + lane * 8 + e] = pw[e];
    }
    __syncthreads();
    return red[t] + red[256 + t] + red[512 + t] + red[768 + t];
}

__global__ __launch_bounds__(256, 1)
void qcqp_fista(const float* __restrict__ P, const float* __restrict__ q,
                const float* __restrict__ ln_, const float* __restrict__ mu,
                float* __restrict__ out)
{
    __shared__ Smem sm;
    const int b = blockIdx.x;
    const int t = threadIdx.x;
    const int c = t >> 5;
    const int r = t & 31;
    const int wave = t >> 6;
    const int lane = t & 63;

    float h[256];
#pragma unroll
    for (int i = 0; i < 256; ++i) h[i] = 0.0f;

    const float* Pb = P + (size_t)b * (NDIM * NDIM);

    // ---- H = P^T P, staged 32 rows of P at a time ----
    for (int chunk = 0; chunk < 8; ++chunk) {
        const float4* src = (const float4*)(Pb + chunk * 8192);
        float4* dst = (float4*)sm.Ps;
#pragma unroll
        for (int it = 0; it < 8; ++it)
            dst[it * 256 + t] = src[it * 256 + t];
        __syncthreads();
#pragma unroll 2
        for (int k = 0; k < 32; ++k) {
            const float4* row = (const float4*)(sm.Ps + k * 256);
            float4 a0 = row[r * 2 + 0];
            float4 a1 = row[r * 2 + 1];
            float ar[8] = {a0.x, a0.y, a0.z, a0.w, a1.x, a1.y, a1.z, a1.w};
            float bc[32];
#pragma unroll
            for (int jj = 0; jj < 8; ++jj) {
                float4 v4 = row[c * 8 + jj];
                bc[jj * 4 + 0] = v4.x; bc[jj * 4 + 1] = v4.y;
                bc[jj * 4 + 2] = v4.z; bc[jj * 4 + 3] = v4.w;
            }
#pragma unroll
            for (int e = 0; e < 8; ++e)
#pragma unroll
                for (int j = 0; j < 32; ++j)
                    h[e * 32 + j] = fmaf(ar[e], bc[j], h[e * 32 + j]);
        }
        __syncthreads();
    }

    // ---- power iteration: v0 = ones; 20x { w = Hv; v = w/(||w||+1e-12) } ----
    sm.vec[t] = 1.0f;
    __syncthreads();
    float vreg = 1.0f;
    for (int it = 0; it < PITERS; ++it) {
        float wi = matvec_row(h, sm.vec, sm.red, t, c, wave, lane);
        float s = wi * wi;
#pragma unroll
        for (int off = 1; off < 64; off <<= 1) s += __shfl_xor(s, off);
        if (lane == 0) sm.scal[wave] = s;
        __syncthreads();
        float tot = sm.scal[0] + sm.scal[1] + sm.scal[2] + sm.scal[3];
        vreg = wi / (sqrtf(tot) + 1e-12f);
        sm.vec[t] = vreg;
        __syncthreads();
    }

    // ---- Rayleigh quotient -> step ----
    float hv = matvec_row(h, sm.vec, sm.red, t, c, wave, lane);
    float n1 = vreg * hv;
    float n2 = vreg * vreg;
#pragma unroll
    for (int off = 1; off < 64; off <<= 1) {
        n1 += __shfl_xor(n1, off);
        n2 += __shfl_xor(n2, off);
    }
    if (lane == 0) { sm.scal[wave] = n1; sm.scal[4 + wave] = n2; }
    __syncthreads();
    float num = sm.scal[0] + sm.scal[1] + sm.scal[2] + sm.scal[3];
    float den = sm.scal[4] + sm.scal[5] + sm.scal[6] + sm.scal[7];
    float L = num / den;
    const float step = 1.0f / (1.05f * fmaxf(L, 1e-12f));

    const float bi = q[b * NDIM + t];
    const float rr = mu[b * NCON + (t >> 1)] * ln_[b * NCON + (t >> 1)];

    // ---- FISTA: l0 = project(0) = 0, y0 = 0, t0 = 1 ----
    float li = 0.0f, yi = 0.0f, tcur = 1.0f;
    __syncthreads();
    sm.vec[t] = 0.0f;
    __syncthreads();

    for (int it = 0; it < FITERS; ++it) {
        float gi = matvec_row(h, sm.vec, sm.red, t, c, wave, lane) + bi;
        float zi = yi - step * gi;
        sm.zz[t] = zi;
        __syncthreads();
        float zp = sm.zz[t ^ 1];
        float nrm = sqrtf(zi * zi + zp * zp);
        float scl = (nrm > rr) ? (rr / fmaxf(nrm, 1e-30f)) : 1.0f;
        float lnew = zi * scl;
        float tn = 0.5f * (1.0f + sqrtf(1.0f + 4.0f * tcur * tcur));
        float ratio = (tcur - 1.0f) / tn;
        float yn = lnew + ratio * (lnew - li);
        li = lnew; tcur = tn; yi = yn;
        sm.vec[t] = yn;
        __syncthreads();
    }

    out[b * NDIM + t] = li;
}

} // namespace

extern "C" void kernel_launch(void* const* d_in, const int* in_sizes, int n_in,
                              void* d_out, int out_size, void* d_ws, size_t ws_size,
                              hipStream_t stream) {
    const float* P   = (const float*)d_in[0];
    const float* q   = (const float*)d_in[1];
    const float* l_n = (const float*)d_in[2];
    const float* mu  = (const float*)d_in[3];
    float* out = (float*)d_out;
    qcqp_fista<<<dim3(512), dim3(256), 0, stream>>>(P, q, l_n, mu, out);
}

// Round 2
// 529.727 us; speedup vs baseline: 1.6463x; 1.6463x over previous
//
#include <hip/hip_runtime.h>
#include <math.h>

// QCQP via FISTA. One 512-thread workgroup per batch; H = P^T P held in
// registers, 128 floats/thread (4 rows x 32 cols), 2 waves/SIMD for latency
// hiding. B=512, N=256, NC=128, 20 power iters, 100 FISTA iters.
//
// Thread t: c = t>>6 (col block: cols c*32..c*32+31, == wave id),
//           r = t&63 (row block: rows 4r..4r+3).
// h[e*32+j] = H[4r+e][c*32+j].

namespace {

constexpr int NDIM = 256;
constexpr int NCON = 128;
constexpr int PITERS = 20;
constexpr int FITERS = 100;
constexpr int RPAD = 260;   // red[] leading-dim pad: stride 260 floats -> 8 partial
                            // reads per output hit distinct banks ((4c+i)%32)

struct Smem {
    float Ps[32 * 256];     // 32 KB P-row staging
    float vec[256];         // v (power) / y (FISTA), broadcast vector
    float red[8 * RPAD];    // cross-wave matvec partials, padded
    float scal[8];          // scalar reductions
};

// (H x)_i for i = t (valid for t < 256), x = sm.vec (barrier-consistent on
// entry). Contains one internal __syncthreads(); all 512 threads must call.
__device__ __forceinline__ float matvec(const float (&h)[128], Smem& sm,
                                        int t, int c, int r)
{
    float xr[32];
    const float4* xp = (const float4*)(sm.vec + c * 32);   // wave-broadcast reads
#pragma unroll
    for (int jj = 0; jj < 8; ++jj) {
        float4 v4 = xp[jj];
        xr[jj * 4 + 0] = v4.x; xr[jj * 4 + 1] = v4.y;
        xr[jj * 4 + 2] = v4.z; xr[jj * 4 + 3] = v4.w;
    }
    float pw[4] = {0.0f, 0.0f, 0.0f, 0.0f};
#pragma unroll
    for (int e = 0; e < 4; ++e)
#pragma unroll
        for (int j = 0; j < 32; ++j)
            pw[e] = fmaf(h[e * 32 + j], xr[j], pw[e]);
    // 1 KB contiguous b128 store per wave (minimum-cycle, conflict-free)
    *(float4*)&sm.red[c * RPAD + r * 4] = make_float4(pw[0], pw[1], pw[2], pw[3]);
    __syncthreads();
    float sum = 0.0f;
    if (t < NDIM) {
#pragma unroll
        for (int c2 = 0; c2 < 8; ++c2) sum += sm.red[c2 * RPAD + t];
    }
    return sum;
}

__global__ __launch_bounds__(512, 2)
void qcqp_fista(const float* __restrict__ P, const float* __restrict__ q,
                const float* __restrict__ ln_, const float* __restrict__ mu,
                float* __restrict__ out)
{
    __shared__ Smem sm;
    const int b = blockIdx.x;
    const int t = threadIdx.x;
    const int c = t >> 6;        // wave id == column block
    const int r = t & 63;        // lane == row block
    const int wave = c;
    const int lane = r;

    float h[128];
#pragma unroll
    for (int i = 0; i < 128; ++i) h[i] = 0.0f;

    const float* Pb = P + (size_t)b * (NDIM * NDIM);

    // ---- H = P^T P, staged 32 rows of P at a time ----
    for (int chunk = 0; chunk < 8; ++chunk) {
        const float4* src = (const float4*)(Pb + chunk * 8192);
        float4* dst = (float4*)sm.Ps;
#pragma unroll
        for (int it = 0; it < 4; ++it)
            dst[it * 512 + t] = src[it * 512 + t];
        __syncthreads();
#pragma unroll 2
        for (int k = 0; k < 32; ++k) {
            const float* row = sm.Ps + k * 256;
            float4 a4 = *(const float4*)(row + r * 4);     // stride-16B lanes
            float ar[4] = {a4.x, a4.y, a4.z, a4.w};
#pragma unroll
            for (int jj = 0; jj < 8; ++jj) {
                float4 bcv = *(const float4*)(row + c * 32 + jj * 4); // broadcast
#pragma unroll
                for (int e = 0; e < 4; ++e) {
                    h[e * 32 + jj * 4 + 0] = fmaf(ar[e], bcv.x, h[e * 32 + jj * 4 + 0]);
                    h[e * 32 + jj * 4 + 1] = fmaf(ar[e], bcv.y, h[e * 32 + jj * 4 + 1]);
                    h[e * 32 + jj * 4 + 2] = fmaf(ar[e], bcv.z, h[e * 32 + jj * 4 + 2]);
                    h[e * 32 + jj * 4 + 3] = fmaf(ar[e], bcv.w, h[e * 32 + jj * 4 + 3]);
                }
            }
        }
        __syncthreads();
    }

    // ---- power iteration: v0 = ones; 20x { w = Hv; v = w/(||w||+1e-12) } ----
    if (t < NDIM) sm.vec[t] = 1.0f;
    __syncthreads();
    float vreg = 1.0f;
    for (int it = 0; it < PITERS; ++it) {
        float wi = matvec(h, sm, t, c, r);
        float s = wi * wi;                       // t>=256: garbage, unused
#pragma unroll
        for (int off = 1; off < 64; off <<= 1) s += __shfl_xor(s, off);
        if (lane == 0 && wave < 4) sm.scal[wave] = s;
        __syncthreads();
        float tot = sm.scal[0] + sm.scal[1] + sm.scal[2] + sm.scal[3];
        if (t < NDIM) {
            vreg = wi / (sqrtf(tot) + 1e-12f);
            sm.vec[t] = vreg;
        }
        __syncthreads();
    }

    // ---- Rayleigh quotient -> step ----
    float hv = matvec(h, sm, t, c, r);
    float n1 = vreg * hv;
    float n2 = vreg * vreg;
    if (t >= NDIM) { n1 = 0.0f; n2 = 0.0f; }
#pragma unroll
    for (int off = 1; off < 64; off <<= 1) {
        n1 += __shfl_xor(n1, off);
        n2 += __shfl_xor(n2, off);
    }
    if (lane == 0 && wave < 4) { sm.scal[wave] = n1; sm.scal[4 + wave] = n2; }
    __syncthreads();
    float num = sm.scal[0] + sm.scal[1] + sm.scal[2] + sm.scal[3];
    float den = sm.scal[4] + sm.scal[5] + sm.scal[6] + sm.scal[7];
    float L = num / den;
    const float step = 1.0f / (1.05f * fmaxf(L, 1e-12f));

    float bi = 0.0f, rr = 0.0f;
    if (t < NDIM) {
        bi = q[b * NDIM + t];
        rr = mu[b * NCON + (t >> 1)] * ln_[b * NCON + (t >> 1)];
    }

    // ---- FISTA: l0 = project(0) = 0, y0 = 0, t0 = 1 ----
    float li = 0.0f, yi = 0.0f, tcur = 1.0f;
    __syncthreads();
    if (t < NDIM) sm.vec[t] = 0.0f;
    __syncthreads();

    for (int it = 0; it < FITERS; ++it) {
        float gsum = matvec(h, sm, t, c, r);
        if (t < NDIM) {                          // waves 0-3 fully active (uniform)
            float gi = gsum + bi;
            float zi = yi - step * gi;
            float zp = __shfl_xor(zi, 1);        // projection partner, same wave
            float nrm = sqrtf(zi * zi + zp * zp);
            float scl = (nrm > rr) ? (rr / fmaxf(nrm, 1e-30f)) : 1.0f;
            float lnew = zi * scl;
            float tn = 0.5f * (1.0f + sqrtf(1.0f + 4.0f * tcur * tcur));
            float ratio = (tcur - 1.0f) / tn;
            float yn = lnew + ratio * (lnew - li);
            li = lnew; tcur = tn; yi = yn;
            sm.vec[t] = yn;
        }
        __syncthreads();
    }

    if (t < NDIM) out[b * NDIM + t] = li;
}

} // namespace

extern "C" void kernel_launch(void* const* d_in, const int* in_sizes, int n_in,
                              void* d_out, int out_size, void* d_ws, size_t ws_size,
                              hipStream_t stream) {
    const float* P   = (const float*)d_in[0];
    const float* q   = (const float*)d_in[1];
    const float* l_n = (const float*)d_in[2];
    const float* mu  = (const float*)d_in[3];
    float* out = (float*)d_out;
    qcqp_fista<<<dim3(512), dim3(512), 0, stream>>>(P, q, l_n, mu, out);
}